// Round 16
// baseline (260.304 us; speedup 1.0000x reference)
//
#include <hip/hip_runtime.h>
#include <hip/hip_bf16.h>

#define T_SEQ 2048
#define NE    1024
#define NH    16
#define HD    64
#define QKV_N 3072
#define MROWS 8192

typedef __attribute__((ext_vector_type(8))) short short8;
typedef __attribute__((ext_vector_type(4))) float f32x4;

__device__ __forceinline__ short f2bf(float f) {
  __hip_bfloat16 h = __float2bfloat16(f);
  return *reinterpret_cast<short*>(&h);
}

// async global->LDS, 16B per lane. LDS dest is WAVE-UNIFORM base + lane*16 (m104);
// swizzled layouts are achieved by pre-swizzling the per-lane GLOBAL source (m173).
__device__ __forceinline__ void lds16(const void* g, void* l) {
  __builtin_amdgcn_global_load_lds(
      (const __attribute__((address_space(1))) unsigned int*)g,
      (__attribute__((address_space(3))) unsigned int*)l, 16, 0, 0);
}

// ---------------- fused prep ----------------
// blocks [0,4096): cvt 8192x1024 x -> xb (each thread exactly one 8-elem group).
// blocks [4096,7168): 32x32 transpose tiles of w_attn[1024][3072] -> wT1[3072][1024].
__global__ __launch_bounds__(256) void prep_fused(const float* __restrict__ x,
                                                  short* __restrict__ xb,
                                                  const float* __restrict__ w_attn,
                                                  short* __restrict__ wT1) {
  __shared__ short tile[32][33];
  const int bid = blockIdx.x;
  if (bid < 4096) {
    const int i = bid * 256 + threadIdx.x;  // 8-elem group index, exact cover
    const float4* s = (const float4*)(x + (size_t)i * 8);
    float4 a = s[0], b = s[1];
    short8 v = short8{f2bf(a.x), f2bf(a.y), f2bf(a.z), f2bf(a.w),
                      f2bf(b.x), f2bf(b.y), f2bf(b.z), f2bf(b.w)};
    *(short8*)(xb + (size_t)i * 8) = v;
  } else {
    const int tb = bid - 4096;          // 0..3071
    const int bn = (tb % 96) * 32;      // over N=3072
    const int bk = (tb / 96) * 32;      // over K=1024
    const int tx = threadIdx.x & 31;
    const int ty = threadIdx.x >> 5;    // 0..7
#pragma unroll
    for (int i = 0; i < 32; i += 8)
      tile[ty + i][tx] = f2bf(w_attn[(size_t)(bk + ty + i) * QKV_N + bn + tx]);
    __syncthreads();
#pragma unroll
    for (int i = 0; i < 32; i += 8)
      wT1[(size_t)(bn + ty + i) * NE + bk + tx] = tile[tx][ty + i];
  }
}

// ---------------- convert + transpose: src[K,N] fp32 -> dst[N,K] bf16 ----------------
__global__ __launch_bounds__(256) void transpose_cvt(const float* __restrict__ src,
                                                     short* __restrict__ dst,
                                                     int K, int N) {
  __shared__ short tile[32][33];
  int bn = blockIdx.x * 32;
  int bk = blockIdx.y * 32;
  int tx = threadIdx.x;  // 0..31
  int ty = threadIdx.y;  // 0..7
#pragma unroll
  for (int i = 0; i < 32; i += 8)
    tile[ty + i][tx] = f2bf(src[(size_t)(bk + ty + i) * N + bn + tx]);
  __syncthreads();
#pragma unroll
  for (int i = 0; i < 32; i += 8)
    dst[(size_t)(bn + ty + i) * K + bk + tx] = tile[tx][ty + i];
}

// ---------------- GEMM: C[M,N] = A[M,K] * Bt[N,K]^T + bias[N] ----------------
// R19-proven BK=64 m97 structure (banked in R10; unchanged).
template <bool OUTF32>
__global__ __launch_bounds__(256) void gemm_bt_bias(const short* __restrict__ A,
                                                    const short* __restrict__ Bt,
                                                    const float* __restrict__ bias,
                                                    void* __restrict__ Co,
                                                    int M, int N, int K) {
  __shared__ __align__(16) short As[128 * 64];
  __shared__ __align__(16) short Bs[128 * 64];

  const int m0 = blockIdx.x * 128;
  const int n0 = blockIdx.y * 128;
  const int tid = threadIdx.x;
  const int w = tid >> 6, lane = tid & 63;
  const int L15 = lane & 15, quad = lane >> 4;
  const int wr = (w >> 1) * 64, wc = (w & 1) * 64;

  const int srow = lane >> 3;  // 0..7 within a wave's 8-row staging slab
  const int sg = lane & 7;     // LDS granule slot this lane fills

  f32x4 acc[4][4] = {};

  for (int k0 = 0; k0 < K; k0 += 64) {
    __syncthreads();  // prior iteration's LDS reads complete before overwrite

#pragma unroll
    for (int p = 0; p < 4; ++p) {
      int r = p * 32 + w * 8 + srow;
      int gl = sg ^ (r & 7);  // inverse-swizzled source granule
      lds16(A + (size_t)(m0 + r) * K + k0 + gl * 8, (char*)As + p * 4096 + w * 1024);
      lds16(Bt + (size_t)(n0 + r) * K + k0 + gl * 8, (char*)Bs + p * 4096 + w * 1024);
    }

    __syncthreads();  // vmcnt(0) drained before barrier -> tiles visible

#pragma unroll
    for (int kk = 0; kk < 2; ++kk) {
      short8 af[4], bfr[4];
#pragma unroll
      for (int i = 0; i < 4; ++i) {
        int r = wr + i * 16 + L15;
        af[i] = *(const short8*)(As + r * 64 + (((kk * 4 + quad) ^ (r & 7)) * 8));
      }
#pragma unroll
      for (int j = 0; j < 4; ++j) {
        int r = wc + j * 16 + L15;
        bfr[j] = *(const short8*)(Bs + r * 64 + (((kk * 4 + quad) ^ (r & 7)) * 8));
      }
#pragma unroll
      for (int i = 0; i < 4; ++i)
#pragma unroll
        for (int j = 0; j < 4; ++j)
          acc[i][j] = __builtin_amdgcn_mfma_f32_16x16x32_bf16(af[i], bfr[j], acc[i][j], 0, 0, 0);
    }
  }

  float bv[4];
#pragma unroll
  for (int j = 0; j < 4; ++j) bv[j] = bias[n0 + wc + j * 16 + L15];
#pragma unroll
  for (int i = 0; i < 4; ++i)
#pragma unroll
    for (int j = 0; j < 4; ++j)
#pragma unroll
      for (int r = 0; r < 4; ++r) {
        size_t row = (size_t)(m0 + wr + i * 16 + quad * 4 + r);
        int col = n0 + wc + j * 16 + L15;
        float v = acc[i][j][r] + bv[j];
        if (OUTF32)
          ((float*)Co)[row * N + col] = v;
        else
          ((short*)Co)[row * N + col] = f2bf(v);
      }
}

// ---------------- MFMA causal flash attention, reduction-free softmax ----------------
// R25: KVBLK=128 (R24's halved barriers) with the bank-conflict fix: V stored as TWO
// 64x80 subtile buffers (Vts[2]) so each subtile's layout is byte-identical to R12's
// proven conflict profile (R15's merged stride-136 layout tripled SQ_LDS_BANK_CONFLICT
// 1.11M -> 3.34M, costing +3.6us). Ks single [128][80] is fine (kr0 shifts a constant).
__global__ __launch_bounds__(256) void attn_flash(const short* __restrict__ qkv,
                                                  short* __restrict__ y) {
  const int bx = blockIdx.x;  // 0..7
  const int bh = blockIdx.y;
  const int b = bh >> 4, h = bh & 15;
  const short* base = qkv + (size_t)b * T_SEQ * QKV_N;
  const int tid = threadIdx.x;
  const int w = tid >> 6, lane = tid & 63;
  const int L15 = lane & 15, quad = lane >> 4;

  __shared__ __align__(16) short Ks[128 * 80];      // [key 0..127][d], pad 80
  __shared__ __align__(16) short Vts[2][64 * 80];   // per-subtile [d][key 0..63], pad 80
  __shared__ __align__(16) short Ps[4][32 * 72];    // per-wave P [q 0..31][key], pad 72

  const short one = (short)0x3F80;
  const short8 vone = short8{one, one, one, one, one, one, one, one};

  const float cs = 0.18033688011112042f;  // (1/sqrt(64)) * log2(e)

  const short* kbase = base + NE + h * HD;
  const short* vbase = base + 2 * NE + h * HD;

  const int skey = tid >> 3;      // 0..31
  const int sd0 = (tid & 7) * 8;  // 0..56
  const int dv0 = w * 8;          // wave w stages d-rows [w*8,w*8+8) and +32

#pragma unroll 1
  for (int seg = 0; seg < 2; ++seg) {
    const int qt = seg == 0 ? (T_SEQ / 128 - 1 - bx) : bx;  // long tile first

    // Q fragments: wave w owns q-rows qt*128 + w*32 + [0,32)
    short8 qf[2][2];
#pragma unroll
    for (int qs = 0; qs < 2; ++qs) {
      const short* qp =
          base + (size_t)(qt * 128 + w * 32 + qs * 16 + L15) * QKV_N + h * HD + quad * 8;
      qf[qs][0] = *(const short8*)qp;
      qf[qs][1] = *(const short8*)(qp + 32);
    }

    f32x4 O[2][4] = {};  // output d-blocks per q-sub-block
    f32x4 L[2] = {};     // rowsum (denominator) per q-sub-block

    // ---- prologue: load 128-key tile 0 into registers ----
    uint4 kv0 = *(const uint4*)(kbase + (size_t)(skey) * QKV_N + sd0);
    uint4 kv1 = *(const uint4*)(kbase + (size_t)(32 + skey) * QKV_N + sd0);
    uint4 kv2 = *(const uint4*)(kbase + (size_t)(64 + skey) * QKV_N + sd0);
    uint4 kv3 = *(const uint4*)(kbase + (size_t)(96 + skey) * QKV_N + sd0);
    uint4 vv0 = *(const uint4*)(vbase + (size_t)lane * QKV_N + dv0);
    uint4 vv1 = *(const uint4*)(vbase + (size_t)lane * QKV_N + dv0 + 32);
    uint4 vv2 = *(const uint4*)(vbase + (size_t)(64 + lane) * QKV_N + dv0);
    uint4 vv3 = *(const uint4*)(vbase + (size_t)(64 + lane) * QKV_N + dv0 + 32);

    const int nkt2 = qt + 1;  // 128-key double-tiles covering keys [0, qt*128+128)
    for (int kt2 = 0; kt2 < nkt2; ++kt2) {
      __syncthreads();  // prior-iteration (or prior-segment) LDS reads complete
      *(uint4*)&Ks[(skey) * 80 + sd0] = kv0;
      *(uint4*)&Ks[(32 + skey) * 80 + sd0] = kv1;
      *(uint4*)&Ks[(64 + skey) * 80 + sd0] = kv2;
      *(uint4*)&Ks[(96 + skey) * 80 + sd0] = kv3;
      {
        const short* p0 = (const short*)&vv0;
        const short* p1 = (const short*)&vv1;
        const short* p2 = (const short*)&vv2;
        const short* p3 = (const short*)&vv3;
#pragma unroll
        for (int j = 0; j < 8; ++j) {
          Vts[0][(dv0 + j) * 80 + lane] = p0[j];
          Vts[0][(32 + dv0 + j) * 80 + lane] = p1[j];
          Vts[1][(dv0 + j) * 80 + lane] = p2[j];
          Vts[1][(32 + dv0 + j) * 80 + lane] = p3[j];
        }
      }
      __syncthreads();

      // ---- issue NEXT 128-key tile's global loads (consumed next iteration) ----
      if (kt2 + 1 < nkt2) {
        const size_t nb0 = (size_t)(kt2 + 1) * 128;
        kv0 = *(const uint4*)(kbase + (nb0 + skey) * QKV_N + sd0);
        kv1 = *(const uint4*)(kbase + (nb0 + 32 + skey) * QKV_N + sd0);
        kv2 = *(const uint4*)(kbase + (nb0 + 64 + skey) * QKV_N + sd0);
        kv3 = *(const uint4*)(kbase + (nb0 + 96 + skey) * QKV_N + sd0);
        vv0 = *(const uint4*)(vbase + (nb0 + lane) * QKV_N + dv0);
        vv1 = *(const uint4*)(vbase + (nb0 + lane) * QKV_N + dv0 + 32);
        vv2 = *(const uint4*)(vbase + (nb0 + 64 + lane) * QKV_N + dv0);
        vv3 = *(const uint4*)(vbase + (nb0 + 64 + lane) * QKV_N + dv0 + 32);
      }

#pragma unroll 1
      for (int sub = 0; sub < 2; ++sub) {
        const int kr0 = sub * 64;  // Ks row offset for this subtile

        // ---- S = Q K^T  (K fragments reused across both q-sub-blocks) ----
        f32x4 S[2][4] = {};
        __builtin_amdgcn_s_setprio(1);
#pragma unroll
        for (int nb = 0; nb < 4; ++nb) {
          short8 kb0 = *(const short8*)&Ks[(kr0 + nb * 16 + L15) * 80 + quad * 8];
          short8 kb1 = *(const short8*)&Ks[(kr0 + nb * 16 + L15) * 80 + 32 + quad * 8];
#pragma unroll
          for (int qs = 0; qs < 2; ++qs) {
            S[qs][nb] = __builtin_amdgcn_mfma_f32_16x16x32_bf16(qf[qs][0], kb0, S[qs][nb], 0, 0, 0);
            S[qs][nb] = __builtin_amdgcn_mfma_f32_16x16x32_bf16(qf[qs][1], kb1, S[qs][nb], 0, 0, 0);
          }
        }
        __builtin_amdgcn_s_setprio(0);

        // ---- causal mask (only the last 128-key tile intersects the diagonal) ----
        if (kt2 == nkt2 - 1) {
#pragma unroll
          for (int qs = 0; qs < 2; ++qs)
#pragma unroll
            for (int nb = 0; nb < 4; ++nb) {
              int kg = kt2 * 128 + kr0 + nb * 16 + L15;
#pragma unroll
              for (int r = 0; r < 4; ++r) {
                int qg = qt * 128 + w * 32 + qs * 16 + quad * 4 + r;
                if (kg > qg) S[qs][nb][r] = -1e30f;
              }
            }
        }

        // ---- p = exp2(S*cs); P: C-layout -> A-layout via WAVE-PRIVATE LDS roundtrip --
        short* myP = &Ps[w][0];
#pragma unroll
        for (int qs = 0; qs < 2; ++qs)
#pragma unroll
          for (int nb = 0; nb < 4; ++nb)
#pragma unroll
            for (int r = 0; r < 4; ++r)
              myP[(qs * 16 + quad * 4 + r) * 72 + nb * 16 + L15] =
                  f2bf(__builtin_amdgcn_exp2f(S[qs][nb][r] * cs));
        asm volatile("" ::: "memory");  // forbid compiler write/read reordering (R9)
        short8 pf[2][2];
#pragma unroll
        for (int qs = 0; qs < 2; ++qs) {
          pf[qs][0] = *(const short8*)&myP[(qs * 16 + L15) * 72 + quad * 8];
          pf[qs][1] = *(const short8*)&myP[(qs * 16 + L15) * 72 + 32 + quad * 8];
        }

        // ---- O += P V (V fragments reused across q-sub-blocks); L += P * ones ----
        __builtin_amdgcn_s_setprio(1);
#pragma unroll
        for (int nb = 0; nb < 4; ++nb) {
          short8 vf0 = *(const short8*)&Vts[sub][(nb * 16 + L15) * 80 + quad * 8];
          short8 vf1 = *(const short8*)&Vts[sub][(nb * 16 + L15) * 80 + 32 + quad * 8];
#pragma unroll
          for (int qs = 0; qs < 2; ++qs) {
            O[qs][nb] = __builtin_amdgcn_mfma_f32_16x16x32_bf16(pf[qs][0], vf0, O[qs][nb], 0, 0, 0);
            O[qs][nb] = __builtin_amdgcn_mfma_f32_16x16x32_bf16(pf[qs][1], vf1, O[qs][nb], 0, 0, 0);
          }
        }
#pragma unroll
        for (int qs = 0; qs < 2; ++qs) {
          L[qs] = __builtin_amdgcn_mfma_f32_16x16x32_bf16(pf[qs][0], vone, L[qs], 0, 0, 0);
          L[qs] = __builtin_amdgcn_mfma_f32_16x16x32_bf16(pf[qs][1], vone, L[qs], 0, 0, 0);
        }
        __builtin_amdgcn_s_setprio(0);
      }
    }

    // ---- epilogue: y = O / l ; l = L[qs][r] (replicated on every lane) ----
#pragma unroll
    for (int qs = 0; qs < 2; ++qs) {
      float inv[4];
#pragma unroll
      for (int r = 0; r < 4; ++r) inv[r] = 1.0f / L[qs][r];
#pragma unroll
      for (int nb = 0; nb < 4; ++nb)
#pragma unroll
        for (int r = 0; r < 4; ++r) {
          size_t row =
              (size_t)b * T_SEQ + (size_t)(qt * 128 + w * 32 + qs * 16 + quad * 4 + r);
          int col = h * HD + nb * 16 + L15;
          y[row * NE + col] = f2bf(O[qs][nb][r] * inv[r]);
        }
    }
  }
}

extern "C" void kernel_launch(void* const* d_in, const int* in_sizes, int n_in,
                              void* d_out, int out_size, void* d_ws, size_t ws_size,
                              hipStream_t stream) {
  (void)in_sizes; (void)n_in; (void)out_size; (void)ws_size;
  const float* x      = (const float*)d_in[0];  // [8192,1024] fp32
  const float* w_attn = (const float*)d_in[1];  // [1024,3072] fp32
  const float* b_attn = (const float*)d_in[2];  // [3072] fp32
  const float* w_proj = (const float*)d_in[3];  // [1024,1024] fp32
  const float* b_proj = (const float*)d_in[4];  // [1024] fp32
  float* out = (float*)d_out;                   // [8192,1024] fp32

  // ws layout (R13-proven, peak 64 MiB via lifetime overlap):
  short* qkv = (short*)d_ws;                      // 8192*3072 bf16 = 48 MiB
  short* wT2 = qkv;                               // 1024*1024 bf16, written AFTER attn
  short* wT1 = qkv + (size_t)MROWS * QKV_N;       // 3072*1024 bf16
  short* y   = wT1;                               // 8192*1024 bf16, written AFTER GEMM1

  // d_out doubles as scratch: xb (16 MiB) dead after GEMM1; GEMM2 overwrites out.
  short* xb = (short*)d_out;

  prep_fused<<<4096 + 3072, 256, 0, stream>>>(x, xb, w_attn, wT1);

  gemm_bt_bias<false><<<dim3(MROWS / 128, QKV_N / 128), 256, 0, stream>>>(
      xb, wT1, b_attn, qkv, MROWS, QKV_N, NE);

  attn_flash<<<dim3(8, 64), 256, 0, stream>>>(qkv, y);

  transpose_cvt<<<dim3(NE / 32, NE / 32), dim3(32, 8), 0, stream>>>(w_proj, wT2, NE, NE);

  gemm_bt_bias<true><<<dim3(MROWS / 128, NE / 128), 256, 0, stream>>>(
      y, wT2, b_proj, out, MROWS, NE, NE);
}

// Round 17
// 248.287 us; speedup vs baseline: 1.0484x; 1.0484x over previous
//
#include <hip/hip_runtime.h>
#include <hip/hip_bf16.h>

#define T_SEQ 2048
#define NE    1024
#define NH    16
#define HD    64
#define QKV_N 3072
#define MROWS 8192

typedef __attribute__((ext_vector_type(8))) short short8;
typedef __attribute__((ext_vector_type(4))) float f32x4;

__device__ __forceinline__ short f2bf(float f) {
  __hip_bfloat16 h = __float2bfloat16(f);
  return *reinterpret_cast<short*>(&h);
}

// async global->LDS, 16B per lane. LDS dest is WAVE-UNIFORM base + lane*16 (m104);
// swizzled layouts are achieved by pre-swizzling the per-lane GLOBAL source (m173).
__device__ __forceinline__ void lds16(const void* g, void* l) {
  __builtin_amdgcn_global_load_lds(
      (const __attribute__((address_space(1))) unsigned int*)g,
      (__attribute__((address_space(3))) unsigned int*)l, 16, 0, 0);
}

// ---------------- fused prep ----------------
// blocks [0,4096): cvt 8192x1024 x -> xb (each thread exactly one 8-elem group).
// blocks [4096,7168): 32x32 transpose tiles of w_attn[1024][3072] -> wT1[3072][1024].
// blocks [7168,8192) (only when wT2e != nullptr): w_proj[1024][1024] -> wT2e.
__global__ __launch_bounds__(256) void prep_fused(const float* __restrict__ x,
                                                  short* __restrict__ xb,
                                                  const float* __restrict__ w_attn,
                                                  short* __restrict__ wT1,
                                                  const float* __restrict__ w_proj,
                                                  short* __restrict__ wT2e) {
  __shared__ short tile[32][33];
  const int bid = blockIdx.x;
  if (bid < 4096) {
    const int i = bid * 256 + threadIdx.x;  // 8-elem group index, exact cover
    const float4* s = (const float4*)(x + (size_t)i * 8);
    float4 a = s[0], b = s[1];
    short8 v = short8{f2bf(a.x), f2bf(a.y), f2bf(a.z), f2bf(a.w),
                      f2bf(b.x), f2bf(b.y), f2bf(b.z), f2bf(b.w)};
    *(short8*)(xb + (size_t)i * 8) = v;
  } else if (bid < 7168) {
    const int tb = bid - 4096;          // 0..3071
    const int bn = (tb % 96) * 32;      // over N=3072
    const int bk = (tb / 96) * 32;      // over K=1024
    const int tx = threadIdx.x & 31;
    const int ty = threadIdx.x >> 5;    // 0..7
#pragma unroll
    for (int i = 0; i < 32; i += 8)
      tile[ty + i][tx] = f2bf(w_attn[(size_t)(bk + ty + i) * QKV_N + bn + tx]);
    __syncthreads();
#pragma unroll
    for (int i = 0; i < 32; i += 8)
      wT1[(size_t)(bn + ty + i) * NE + bk + tx] = tile[tx][ty + i];
  } else {
    const int tb = bid - 7168;          // 0..1023
    const int bn = (tb & 31) * 32;      // over N=1024
    const int bk = (tb >> 5) * 32;      // over K=1024
    const int tx = threadIdx.x & 31;
    const int ty = threadIdx.x >> 5;    // 0..7
#pragma unroll
    for (int i = 0; i < 32; i += 8)
      tile[ty + i][tx] = f2bf(w_proj[(size_t)(bk + ty + i) * NE + bn + tx]);
    __syncthreads();
#pragma unroll
    for (int i = 0; i < 32; i += 8)
      wT2e[(size_t)(bn + ty + i) * NE + bk + tx] = tile[tx][ty + i];
  }
}

// ---------------- convert + transpose: src[K,N] fp32 -> dst[N,K] bf16 ----------------
__global__ __launch_bounds__(256) void transpose_cvt(const float* __restrict__ src,
                                                     short* __restrict__ dst,
                                                     int K, int N) {
  __shared__ short tile[32][33];
  int bn = blockIdx.x * 32;
  int bk = blockIdx.y * 32;
  int tx = threadIdx.x;  // 0..31
  int ty = threadIdx.y;  // 0..7
#pragma unroll
  for (int i = 0; i < 32; i += 8)
    tile[ty + i][tx] = f2bf(src[(size_t)(bk + ty + i) * N + bn + tx]);
  __syncthreads();
#pragma unroll
  for (int i = 0; i < 32; i += 8)
    dst[(size_t)(bn + ty + i) * K + bk + tx] = tile[tx][ty + i];
}

// ---------------- GEMM: C[M,N] = A[M,K] * Bt[N,K]^T + bias[N] ----------------
// R19-proven BK=64 m97 structure (banked in R10; unchanged).
template <bool OUTF32>
__global__ __launch_bounds__(256) void gemm_bt_bias(const short* __restrict__ A,
                                                    const short* __restrict__ Bt,
                                                    const float* __restrict__ bias,
                                                    void* __restrict__ Co,
                                                    int M, int N, int K) {
  __shared__ __align__(16) short As[128 * 64];
  __shared__ __align__(16) short Bs[128 * 64];

  const int m0 = blockIdx.x * 128;
  const int n0 = blockIdx.y * 128;
  const int tid = threadIdx.x;
  const int w = tid >> 6, lane = tid & 63;
  const int L15 = lane & 15, quad = lane >> 4;
  const int wr = (w >> 1) * 64, wc = (w & 1) * 64;

  const int srow = lane >> 3;  // 0..7 within a wave's 8-row staging slab
  const int sg = lane & 7;     // LDS granule slot this lane fills

  f32x4 acc[4][4] = {};

  for (int k0 = 0; k0 < K; k0 += 64) {
    __syncthreads();  // prior iteration's LDS reads complete before overwrite

#pragma unroll
    for (int p = 0; p < 4; ++p) {
      int r = p * 32 + w * 8 + srow;
      int gl = sg ^ (r & 7);  // inverse-swizzled source granule
      lds16(A + (size_t)(m0 + r) * K + k0 + gl * 8, (char*)As + p * 4096 + w * 1024);
      lds16(Bt + (size_t)(n0 + r) * K + k0 + gl * 8, (char*)Bs + p * 4096 + w * 1024);
    }

    __syncthreads();  // vmcnt(0) drained before barrier -> tiles visible

#pragma unroll
    for (int kk = 0; kk < 2; ++kk) {
      short8 af[4], bfr[4];
#pragma unroll
      for (int i = 0; i < 4; ++i) {
        int r = wr + i * 16 + L15;
        af[i] = *(const short8*)(As + r * 64 + (((kk * 4 + quad) ^ (r & 7)) * 8));
      }
#pragma unroll
      for (int j = 0; j < 4; ++j) {
        int r = wc + j * 16 + L15;
        bfr[j] = *(const short8*)(Bs + r * 64 + (((kk * 4 + quad) ^ (r & 7)) * 8));
      }
#pragma unroll
      for (int i = 0; i < 4; ++i)
#pragma unroll
        for (int j = 0; j < 4; ++j)
          acc[i][j] = __builtin_amdgcn_mfma_f32_16x16x32_bf16(af[i], bfr[j], acc[i][j], 0, 0, 0);
    }
  }

  float bv[4];
#pragma unroll
  for (int j = 0; j < 4; ++j) bv[j] = bias[n0 + wc + j * 16 + L15];
#pragma unroll
  for (int i = 0; i < 4; ++i)
#pragma unroll
    for (int j = 0; j < 4; ++j)
#pragma unroll
      for (int r = 0; r < 4; ++r) {
        size_t row = (size_t)(m0 + wr + i * 16 + quad * 4 + r);
        int col = n0 + wc + j * 16 + L15;
        float v = acc[i][j][r] + bv[j];
        if (OUTF32)
          ((float*)Co)[row * N + col] = v;
        else
          ((short*)Co)[row * N + col] = f2bf(v);
      }
}

// ---------------- MFMA causal flash attention, reduction-free softmax ----------------
// R12-proven best (81.8us in-dispatch): 64-key tile, 4 waves x 32 q-rows, balanced
// pairs (15-bx, bx) -> 34 uniform k-iters, reg-prefetch staging, in-kernel V
// transpose, 2 barriers/tile, T5 setprio around MFMA clusters. KVBLK=128 refuted
// in both layouts (R15: conflicts 3x; R16: conflicts fixed but still 84-85us --
// deeper prefetch costs issue efficiency). This is the tested local optimum.
__global__ __launch_bounds__(256) void attn_flash(const short* __restrict__ qkv,
                                                  short* __restrict__ y) {
  const int bx = blockIdx.x;  // 0..7
  const int bh = blockIdx.y;
  const int b = bh >> 4, h = bh & 15;
  const short* base = qkv + (size_t)b * T_SEQ * QKV_N;
  const int tid = threadIdx.x;
  const int w = tid >> 6, lane = tid & 63;
  const int L15 = lane & 15, quad = lane >> 4;

  __shared__ __align__(16) short Ks[64 * 80];     // [key][d], pad 80
  __shared__ __align__(16) short Vts[64 * 80];    // [d][key], pad 80
  __shared__ __align__(16) short Ps[4][32 * 72];  // per-wave P [q 0..31][key], pad 72

  const short one = (short)0x3F80;
  const short8 vone = short8{one, one, one, one, one, one, one, one};

  const float cs = 0.18033688011112042f;  // (1/sqrt(64)) * log2(e)

  const short* kbase = base + NE + h * HD;
  const short* vbase = base + 2 * NE + h * HD;

  const int skey = tid >> 3;      // 0..31
  const int sd0 = (tid & 7) * 8;  // 0..56
  const int dv0 = w * 8;          // wave w stages d-rows [w*8,w*8+8) and +32

#pragma unroll 1
  for (int seg = 0; seg < 2; ++seg) {
    const int qt = seg == 0 ? (T_SEQ / 128 - 1 - bx) : bx;  // long tile first

    // Q fragments: wave w owns q-rows qt*128 + w*32 + [0,32)
    short8 qf[2][2];
#pragma unroll
    for (int qs = 0; qs < 2; ++qs) {
      const short* qp =
          base + (size_t)(qt * 128 + w * 32 + qs * 16 + L15) * QKV_N + h * HD + quad * 8;
      qf[qs][0] = *(const short8*)qp;
      qf[qs][1] = *(const short8*)(qp + 32);
    }

    f32x4 O[2][4] = {};  // output d-blocks per q-sub-block
    f32x4 L[2] = {};     // rowsum (denominator) per q-sub-block

    // ---- prologue: load tile 0 into registers ----
    uint4 kv0 = *(const uint4*)(kbase + (size_t)skey * QKV_N + sd0);
    uint4 kv1 = *(const uint4*)(kbase + (size_t)(32 + skey) * QKV_N + sd0);
    uint4 vv0 = *(const uint4*)(vbase + (size_t)lane * QKV_N + dv0);
    uint4 vv1 = *(const uint4*)(vbase + (size_t)lane * QKV_N + dv0 + 32);

    const int nkt = 2 * qt + 2;  // k-tiles covering keys [0, qt*128+128)
    for (int kt = 0; kt < nkt; ++kt) {
      __syncthreads();  // prior-iteration (or prior-segment) LDS reads complete
      *(uint4*)&Ks[skey * 80 + sd0] = kv0;
      *(uint4*)&Ks[(32 + skey) * 80 + sd0] = kv1;
      {
        const short* pv0 = (const short*)&vv0;
        const short* pv1 = (const short*)&vv1;
#pragma unroll
        for (int j = 0; j < 8; ++j) {
          Vts[(dv0 + j) * 80 + lane] = pv0[j];
          Vts[(32 + dv0 + j) * 80 + lane] = pv1[j];
        }
      }
      __syncthreads();

      // ---- issue NEXT tile's global loads (consumed next iteration) ----
      if (kt < nkt - 1) {
        int nt = kt + 1;
        kv0 = *(const uint4*)(kbase + (size_t)(nt * 64 + skey) * QKV_N + sd0);
        kv1 = *(const uint4*)(kbase + (size_t)(nt * 64 + 32 + skey) * QKV_N + sd0);
        vv0 = *(const uint4*)(vbase + (size_t)(nt * 64 + lane) * QKV_N + dv0);
        vv1 = *(const uint4*)(vbase + (size_t)(nt * 64 + lane) * QKV_N + dv0 + 32);
      }

      // ---- S = Q K^T  (K fragments reused across both q-sub-blocks) ----
      f32x4 S[2][4] = {};
      __builtin_amdgcn_s_setprio(1);
#pragma unroll
      for (int nb = 0; nb < 4; ++nb) {
        short8 kb0 = *(const short8*)&Ks[(nb * 16 + L15) * 80 + quad * 8];
        short8 kb1 = *(const short8*)&Ks[(nb * 16 + L15) * 80 + 32 + quad * 8];
#pragma unroll
        for (int qs = 0; qs < 2; ++qs) {
          S[qs][nb] = __builtin_amdgcn_mfma_f32_16x16x32_bf16(qf[qs][0], kb0, S[qs][nb], 0, 0, 0);
          S[qs][nb] = __builtin_amdgcn_mfma_f32_16x16x32_bf16(qf[qs][1], kb1, S[qs][nb], 0, 0, 0);
        }
      }
      __builtin_amdgcn_s_setprio(0);

      // ---- causal mask (only the last two k-tiles can intersect the diagonal) ----
      if (kt >= nkt - 2) {
#pragma unroll
        for (int qs = 0; qs < 2; ++qs)
#pragma unroll
          for (int nb = 0; nb < 4; ++nb) {
            int kg = kt * 64 + nb * 16 + L15;
#pragma unroll
            for (int r = 0; r < 4; ++r) {
              int qg = qt * 128 + w * 32 + qs * 16 + quad * 4 + r;
              if (kg > qg) S[qs][nb][r] = -1e30f;
            }
          }
      }

      // ---- p = exp2(S*cs); P: C-layout -> A-layout via WAVE-PRIVATE LDS round trip ----
      short* myP = &Ps[w][0];
#pragma unroll
      for (int qs = 0; qs < 2; ++qs)
#pragma unroll
        for (int nb = 0; nb < 4; ++nb)
#pragma unroll
          for (int r = 0; r < 4; ++r)
            myP[(qs * 16 + quad * 4 + r) * 72 + nb * 16 + L15] =
                f2bf(__builtin_amdgcn_exp2f(S[qs][nb][r] * cs));
      asm volatile("" ::: "memory");  // forbid compiler write/read reordering (R9-proven)
      short8 pf[2][2];
#pragma unroll
      for (int qs = 0; qs < 2; ++qs) {
        pf[qs][0] = *(const short8*)&myP[(qs * 16 + L15) * 72 + quad * 8];
        pf[qs][1] = *(const short8*)&myP[(qs * 16 + L15) * 72 + 32 + quad * 8];
      }

      // ---- O += P V (V fragments reused across q-sub-blocks); L += P * ones ----
      __builtin_amdgcn_s_setprio(1);
#pragma unroll
      for (int nb = 0; nb < 4; ++nb) {
        short8 vf0 = *(const short8*)&Vts[(nb * 16 + L15) * 80 + quad * 8];
        short8 vf1 = *(const short8*)&Vts[(nb * 16 + L15) * 80 + 32 + quad * 8];
#pragma unroll
        for (int qs = 0; qs < 2; ++qs) {
          O[qs][nb] = __builtin_amdgcn_mfma_f32_16x16x32_bf16(pf[qs][0], vf0, O[qs][nb], 0, 0, 0);
          O[qs][nb] = __builtin_amdgcn_mfma_f32_16x16x32_bf16(pf[qs][1], vf1, O[qs][nb], 0, 0, 0);
        }
      }
#pragma unroll
      for (int qs = 0; qs < 2; ++qs) {
        L[qs] = __builtin_amdgcn_mfma_f32_16x16x32_bf16(pf[qs][0], vone, L[qs], 0, 0, 0);
        L[qs] = __builtin_amdgcn_mfma_f32_16x16x32_bf16(pf[qs][1], vone, L[qs], 0, 0, 0);
      }
      __builtin_amdgcn_s_setprio(0);
    }

    // ---- epilogue: y = O / l ; l = L[qs][r] (replicated on every lane) ----
#pragma unroll
    for (int qs = 0; qs < 2; ++qs) {
      float inv[4];
#pragma unroll
      for (int r = 0; r < 4; ++r) inv[r] = 1.0f / L[qs][r];
#pragma unroll
      for (int nb = 0; nb < 4; ++nb)
#pragma unroll
        for (int r = 0; r < 4; ++r) {
          size_t row =
              (size_t)b * T_SEQ + (size_t)(qt * 128 + w * 32 + qs * 16 + quad * 4 + r);
          int col = h * HD + nb * 16 + L15;
          y[row * NE + col] = f2bf(O[qs][nb][r] * inv[r]);
        }
    }
  }
}

extern "C" void kernel_launch(void* const* d_in, const int* in_sizes, int n_in,
                              void* d_out, int out_size, void* d_ws, size_t ws_size,
                              hipStream_t stream) {
  (void)in_sizes; (void)n_in; (void)out_size;
  const float* x      = (const float*)d_in[0];  // [8192,1024] fp32
  const float* w_attn = (const float*)d_in[1];  // [1024,3072] fp32
  const float* b_attn = (const float*)d_in[2];  // [3072] fp32
  const float* w_proj = (const float*)d_in[3];  // [1024,1024] fp32
  const float* b_proj = (const float*)d_in[4];  // [1024] fp32
  float* out = (float*)d_out;                   // [8192,1024] fp32

  // ws layout (R13-proven, peak 64 MiB via lifetime overlap):
  short* qkv = (short*)d_ws;                      // 8192*3072 bf16 = 48 MiB
  short* wT2 = qkv;                               // 1024*1024 bf16, written AFTER attn
  short* wT1 = qkv + (size_t)MROWS * QKV_N;       // 3072*1024 bf16
  short* y   = wT1;                               // 8192*1024 bf16, written AFTER GEMM1

  // d_out doubles as scratch: xb (16 MiB) dead after GEMM1; GEMM2 overwrites out.
  short* xb = (short*)d_out;

  // Guarded wproj-fusion: if workspace has >= 2 MiB beyond the 64 MiB layout,
  // transpose w_proj inside prep_fused and skip the separate transpose_cvt launch.
  const size_t base64 = (size_t)64 * 1024 * 1024;
  const bool fuse_wproj = ws_size >= base64 + (size_t)2 * 1024 * 1024;
  short* wT2e = fuse_wproj ? (short*)((char*)d_ws + base64) : nullptr;

  prep_fused<<<fuse_wproj ? 8192 : 7168, 256, 0, stream>>>(x, xb, w_attn, wT1, w_proj, wT2e);

  gemm_bt_bias<false><<<dim3(MROWS / 128, QKV_N / 128), 256, 0, stream>>>(
      xb, wT1, b_attn, qkv, MROWS, QKV_N, NE);

  attn_flash<<<dim3(8, 64), 256, 0, stream>>>(qkv, y);

  const short* wB2;
  if (fuse_wproj) {
    wB2 = wT2e;
  } else {
    transpose_cvt<<<dim3(NE / 32, NE / 32), dim3(32, 8), 0, stream>>>(w_proj, wT2, NE, NE);
    wB2 = wT2;
  }

  gemm_bt_bias<true><<<dim3(MROWS / 128, NE / 128), 256, 0, stream>>>(
      y, wB2, b_proj, out, MROWS, NE, NE);
}